// Round 2
// baseline (1107.374 us; speedup 1.0000x reference)
//
#include <hip/hip_runtime.h>
#include <hip/hip_bf16.h>
#include <math.h>

typedef __hip_bfloat16 bf16;
typedef float f32x4 __attribute__((ext_vector_type(4)));
typedef short bf16x8 __attribute__((ext_vector_type(8)));

#define NNODES 4095
#define BATCH 64
#define NUM_OPS 20
#define TEMP 3.0f

// workspace layout (bytes)
#define OFF_WBIGT 0x000000ull              // 1280*640*2 = 1,638,400 B
#define OFF_BIAS  0x190000ull              // 1280*4
#define OFF_HA    0x200000ull              // 64 MiB  (levels 11,9,7,...)
#define OFF_CA    (OFF_HA + (64ull<<20))   // 64 MiB
#define OFF_HB    (OFF_CA + (64ull<<20))   // 32 MiB  (levels 10,8,...,0)
#define OFF_CB    (OFF_HB + (32ull<<20))   // 32 MiB
// total = 194 MiB

__device__ __forceinline__ float sigmoid_f(float x) {
    return 1.0f / (1.0f + __expf(-x));
}
__device__ __forceinline__ float tanh_f(float x) {
    return 1.0f - 2.0f / (__expf(2.0f * x) + 1.0f);
}

// direct global->LDS DMA, 16 B per lane; LDS dest is wave-uniform base + lane*16
__device__ __forceinline__ void async_copy16(const bf16* g, bf16* l) {
    __builtin_amdgcn_global_load_lds(
        (const __attribute__((address_space(1))) void*)g,
        (__attribute__((address_space(3))) void*)l,
        16, 0, 0);
}

// Build WbigT[n][k] (bf16, n in [0,1280), k in [0,640)) and biasCat[1280].
// k<128: x rows (Wiou | Wf dup); k in [128,384): even child; [384,640): odd child.
// n = g*256 + ch with gates g: 0=i,1=o,2=u,3=f0,4=f1.
__global__ void init_weights(const float* __restrict__ Wiou,
                             const float* __restrict__ biou,
                             const float* __restrict__ Uiou,
                             const float* __restrict__ Wf,
                             const float* __restrict__ bfv,
                             const float* __restrict__ Uf,
                             bf16* __restrict__ wbigT,
                             float* __restrict__ biasCat)
{
    int idx = blockIdx.x * 256 + threadIdx.x;
    if (idx < 1280 * 640) {
        int k = idx % 640;
        int n = idx / 640;
        int g = n >> 8;
        int ch = n & 255;
        float v;
        if (k < 128) {
            v = (g < 3) ? Wiou[k * 768 + n] : Wf[k * 256 + ch];
        } else {
            int par = (k < 384) ? 0 : 1;
            int hh = (k - 128) & 255;
            if (g < 3) v = Uiou[(par * 256 + hh) * 768 + n];
            else {
                int kk = g - 3;
                v = Uf[(((kk * 2 + par) * 256) + hh) * 256 + ch];
            }
        }
        wbigT[(size_t)n * 640 + k] = __float2bfloat16(v);
    }
    if (idx < 1280) {
        biasCat[idx] = (idx < 768) ? biou[idx] : bfv[idx & 255];
    }
}

// One tree level. Rows r = b*m + j (parents). A row = [x(128) | h_even | h_odd].
// Block tile: 128 rows x 32 channels x NG gate col-tiles (spaced 256 apart),
// so each lane holds i,o,u,f0,f1 for its (row,ch) in registers -> fused epilogue.
// LDS layout is chunk-major [k-chunk][row][8 elems]: lane-linear 16B slots
// (global_load_lds compatible) AND bank-conflict-free b128 fragment reads.
template <bool LEAF>
__global__ __launch_bounds__(256, 4)
void level_kernel(const float* __restrict__ arg_hot,
                  const bf16* __restrict__ wbigT,
                  const float* __restrict__ biasCat,
                  const bf16* __restrict__ h_child,   // [(2M) rows][256]
                  const bf16* __restrict__ c_child,
                  bf16* __restrict__ h_out,           // [M rows][256]
                  bf16* __restrict__ c_out,
                  int m, int logm)
{
    constexpr int NG = LEAF ? 3 : 5;
    constexpr int KI = LEAF ? 2 : 10;    // k-blocks of 64
    constexpr int BROWS = NG * 32;       // B n-rows per block
    constexpr int BINSTR = (BROWS * 8) / 256;  // global_load_lds instrs per wave (3 or 5)

    const int M = BATCH * m;
    const int node_base = m - 1;

    __shared__ bf16 As[8][128][8];       // 16 KB
    __shared__ bf16 Bs[8][BROWS][8];     // 12 KB (leaf) / 20 KB (interior)

    const int tid = threadIdx.x;

    // block swizzle: the 8 ch-blocks sharing an A m-tile land consecutive on one XCD
    int bid = blockIdx.x;
    int mtiles = gridDim.x >> 3;
    int mtile, chblk;
    if ((mtiles & 7) == 0) {
        int xcd = bid & 7;
        int seq = bid >> 3;
        chblk = seq & 7;
        mtile = ((seq >> 3) << 3) + xcd;
    } else {
        mtile = bid >> 3;
        chblk = bid & 7;
    }
    const int rbase  = mtile * 128;
    const int chbase = chblk * 32;

    const int lane = tid & 63;
    const int wave = tid >> 6;
    const int wr = wave & 1;   // row half (64 rows)
    const int wc = wave >> 1;  // channel half (16 ch)
    const int l15 = lane & 15;
    const int lq  = lane >> 4;

    f32x4 acc[4][NG];
#pragma unroll
    for (int a = 0; a < 4; ++a)
#pragma unroll
        for (int g = 0; g < NG; ++g)
            acc[a][g] = (f32x4){0.f, 0.f, 0.f, 0.f};

    // per-lane B source offsets (elements into wbigT), one per instruction
    int boff[BINSTR];
#pragma unroll
    for (int i = 0; i < BINSTR; ++i) {
        int slot  = wave * (BINSTR * 64) + i * 64 + lane;  // linear slot in Bs
        int chunk = slot / BROWS;
        int brow  = slot % BROWS;
        int ncol  = (brow >> 5) * 256 + chbase + (brow & 31);
        boff[i] = ncol * 640 + chunk * 8;
    }

    // x staging source row (clamped for l=0 partial tile)
    const int arow = tid & 127;
    const int rs = min(rbase + arow, M - 1);
    const float* xrow = arg_hot +
        ((size_t)(rs >> logm) * NNODES + node_base + (rs & (m - 1))) * 128;

    for (int kb = 0; kb < KI; ++kb) {
        // ---- stage A ----
        if (LEAF || kb < 2) {
            // x region: fp32 -> bf16, packed converts, b128 LDS writes.
            // thread t writes slots {t, t+256, t+512, t+768}: conflict-free.
            const float* xk = xrow + kb * 64;
#pragma unroll
            for (int j = 0; j < 4; ++j) {
                int chunk = (tid >> 7) + 2 * j;
                const float* src = xk + chunk * 8;
                float4 a = *(const float4*)src;
                float4 b = *(const float4*)(src + 4);
                union { int4 i4; __hip_bfloat162 h2[4]; } u;
                u.h2[0] = __float22bfloat162_rn(make_float2(a.x, a.y));
                u.h2[1] = __float22bfloat162_rn(make_float2(a.z, a.w));
                u.h2[2] = __float22bfloat162_rn(make_float2(b.x, b.y));
                u.h2[3] = __float22bfloat162_rn(make_float2(b.z, b.w));
                *(int4*)&As[chunk][arow][0] = u.i4;
            }
        } else {
            // h region: direct global->LDS DMA (bf16 passthrough)
            const bf16* abase = h_child + (size_t)(rbase + lane) * 512 + (kb * 64 - 128);
#pragma unroll
            for (int i = 0; i < 4; ++i) {
                int chunk = wave * 2 + (i >> 1);
                int rowb  = (i & 1) * 64;
                async_copy16(abase + rowb * 512 + chunk * 8, &As[chunk][rowb][0]);
            }
        }
        // ---- stage B: direct global->LDS DMA ----
#pragma unroll
        for (int i = 0; i < BINSTR; ++i) {
            const bf16* src = wbigT + boff[i] + kb * 64;
            bf16* dst = ((bf16*)Bs) + (size_t)(wave * BINSTR + i) * 64 * 8;
            async_copy16(src, dst);
        }
        __syncthreads();
        // ---- compute: 2 k-steps of 32, 4 x NG MFMAs each ----
#pragma unroll
        for (int ks = 0; ks < 2; ++ks) {
            bf16x8 af[4];
#pragma unroll
            for (int rt = 0; rt < 4; ++rt)
                af[rt] = *(const bf16x8*)&As[ks * 4 + lq][wr * 64 + rt * 16 + l15][0];
#pragma unroll
            for (int g = 0; g < NG; ++g) {
                bf16x8 bfr = *(const bf16x8*)&Bs[ks * 4 + lq][g * 32 + wc * 16 + l15][0];
#pragma unroll
                for (int rt = 0; rt < 4; ++rt)
                    acc[rt][g] = __builtin_amdgcn_mfma_f32_16x16x32_bf16(
                        af[rt], bfr, acc[rt][g], 0, 0, 0);
            }
        }
        __syncthreads();
    }

    // ---- fused LSTM-cell epilogue (all gates in-register per lane) ----
    const int ch = chbase + wc * 16 + l15;
    const float b_i = biasCat[ch];
    const float b_o = biasCat[256 + ch];
    const float b_u = biasCat[512 + ch];
    const float b_f = LEAF ? 0.f : biasCat[768 + ch];

#pragma unroll
    for (int rt = 0; rt < 4; ++rt) {
#pragma unroll
        for (int ri = 0; ri < 4; ++ri) {
            int r = rbase + wr * 64 + rt * 16 + lq * 4 + ri;
            if (r < M) {
                float i = sigmoid_f(acc[rt][0][ri] + b_i);
                float o = sigmoid_f(acc[rt][1][ri] + b_o);
                float u = tanh_f(acc[rt][2][ri] + b_u);
                float cn;
                if (LEAF) {
                    cn = i * u;
                } else {
                    float f0 = sigmoid_f(acc[rt][3][ri] + b_f);
                    float f1 = sigmoid_f(acc[rt][4][ri] + b_f);
                    float c0 = __bfloat162float(c_child[(size_t)r * 512 + ch]);
                    float c1 = __bfloat162float(c_child[(size_t)r * 512 + 256 + ch]);
                    cn = i * u + f0 * c0 + f1 * c1;
                }
                float h = o * tanh_f(cn);
                h_out[(size_t)r * 256 + ch] = __float2bfloat16(h);
                c_out[(size_t)r * 256 + ch] = __float2bfloat16(cn);
            }
        }
    }
}

// actor head: logits = log(mask) + (h.w + b)*mask; softmax(logits/TEMP)
__global__ void head_kernel(const bf16* __restrict__ rootH,
                            const float* __restrict__ actor_w,
                            const float* __restrict__ actor_b,
                            const float* __restrict__ vmask,
                            float* __restrict__ out)
{
    int b = blockIdx.x;
    __shared__ float logits[NUM_OPS];
    int t = threadIdx.x;
    if (t < NUM_OPS) {
        const bf16* hr = rootH + b * 256;
        const float* w = actor_w + t * 256;
        float dot = 0.f;
        for (int hh = 0; hh < 256; ++hh)
            dot += __bfloat162float(hr[hh]) * w[hh];
        float mk = vmask[b * NUM_OPS + t];
        float lg = (mk > 0.f) ? (logf(mk) + (dot + actor_b[t]) * mk) : -INFINITY;
        logits[t] = lg / TEMP;
    }
    __syncthreads();
    if (t == 0) {
        float mx = -INFINITY;
        for (int o = 0; o < NUM_OPS; ++o) mx = fmaxf(mx, logits[o]);
        float s = 0.f;
        float e[NUM_OPS];
        for (int o = 0; o < NUM_OPS; ++o) { e[o] = __expf(logits[o] - mx); s += e[o]; }
        float inv = 1.f / s;
        for (int o = 0; o < NUM_OPS; ++o) out[b * NUM_OPS + o] = e[o] * inv;
    }
}

extern "C" void kernel_launch(void* const* d_in, const int* in_sizes, int n_in,
                              void* d_out, int out_size, void* d_ws, size_t ws_size,
                              hipStream_t stream)
{
    const float* arg_hot = (const float*)d_in[0];
    const float* Wiou    = (const float*)d_in[1];
    const float* biou    = (const float*)d_in[2];
    const float* Uiou    = (const float*)d_in[3];
    const float* Wf      = (const float*)d_in[4];
    const float* bfv     = (const float*)d_in[5];
    const float* Uf      = (const float*)d_in[6];
    const float* actor_w = (const float*)d_in[7];
    const float* actor_b = (const float*)d_in[8];
    const float* vmask   = (const float*)d_in[9];

    char* ws = (char*)d_ws;
    bf16*  wbigT   = (bf16*)(ws + OFF_WBIGT);
    float* biasCat = (float*)(ws + OFF_BIAS);
    bf16*  hA = (bf16*)(ws + OFF_HA);
    bf16*  cA = (bf16*)(ws + OFF_CA);
    bf16*  hB = (bf16*)(ws + OFF_HB);
    bf16*  cB = (bf16*)(ws + OFF_CB);

    init_weights<<<dim3((1280 * 640 + 255) / 256), 256, 0, stream>>>(
        Wiou, biou, Uiou, Wf, bfv, Uf, wbigT, biasCat);

    // leaf level (l=11): m=2048, K=128, writes buffers A
    {
        int m = 2048;
        int mtiles = (BATCH * m + 127) / 128;   // 1024
        level_kernel<true><<<dim3(mtiles * 8), 256, 0, stream>>>(
            arg_hot, wbigT, biasCat, nullptr, nullptr, hA, cA, m, 11);
    }
    // interior levels 10..0
    for (int l = 10; l >= 0; --l) {
        int m = 1 << l;
        int mtiles = (BATCH * m + 127) / 128;
        bf16 *hc, *cc, *ho, *co;
        if (l & 1) { hc = hB; cc = cB; ho = hA; co = cA; }
        else       { hc = hA; cc = cA; ho = hB; co = cB; }
        level_kernel<false><<<dim3(mtiles * 8), 256, 0, stream>>>(
            arg_hot, wbigT, biasCat, hc, cc, ho, co, m, l);
    }
    // root h is in hB (level 0 writes B)
    head_kernel<<<dim3(BATCH), 64, 0, stream>>>(hB, actor_w, actor_b, vmask, (float*)d_out);
}

// Round 3
// 902.428 us; speedup vs baseline: 1.2271x; 1.2271x over previous
//
#include <hip/hip_runtime.h>
#include <hip/hip_bf16.h>
#include <math.h>

typedef __hip_bfloat16 bf16;
typedef float f32x4 __attribute__((ext_vector_type(4)));
typedef short bf16x8 __attribute__((ext_vector_type(8)));

#define NNODES 4095
#define BATCH 64
#define NUM_OPS 20
#define TEMP 3.0f

// workspace layout (bytes)
#define OFF_WTILE 0x000000ull              // 1280*640*2 = 1,638,400 B (pre-tiled)
#define OFF_BIAS  0x190000ull              // 1280*4
#define OFF_HA    0x200000ull              // 64 MiB  (levels 11,9,7,...)
#define OFF_CA    (OFF_HA + (64ull<<20))   // 64 MiB
#define OFF_HB    (OFF_CA + (64ull<<20))   // 32 MiB  (levels 10,8,...,0)
#define OFF_CB    (OFF_HB + (32ull<<20))   // 32 MiB
// total = 194 MiB

__device__ __forceinline__ float sigmoid_f(float x) {
    return 1.0f / (1.0f + __expf(-x));
}
__device__ __forceinline__ float tanh_f(float x) {
    return 1.0f - 2.0f / (__expf(2.0f * x) + 1.0f);
}

// direct global->LDS DMA, 16 B per lane; LDS dest = wave-uniform base + lane*16
__device__ __forceinline__ void async_copy16(const bf16* g, bf16* l) {
    __builtin_amdgcn_global_load_lds(
        (const __attribute__((address_space(1))) void*)g,
        (__attribute__((address_space(3))) void*)l,
        16, 0, 0);
}

// Pre-tile weights into the exact per-(chblk,kb) LDS image:
//   wtile[chblk][kb][chunk(8)][brow(160)][8]   (bf16, 20480 B per tile)
// brow = g*32 + cl, gates g: 0=i,1=o,2=u,3=f0,4=f1; ch = chblk*32+cl.
// k<128: x rows (Wiou | Wf dup); k in [128,384): even child; [384,640): odd.
__global__ void init_weights(const float* __restrict__ Wiou,
                             const float* __restrict__ biou,
                             const float* __restrict__ Uiou,
                             const float* __restrict__ Wf,
                             const float* __restrict__ bfv,
                             const float* __restrict__ Uf,
                             bf16* __restrict__ wtile,
                             float* __restrict__ biasCat)
{
    int idx = blockIdx.x * 256 + threadIdx.x;
    if (idx < 1280 * 640) {
        int k = idx % 640;
        int n = idx / 640;
        int g = n >> 8;
        int ch = n & 255;
        float v;
        if (k < 128) {
            v = (g < 3) ? Wiou[k * 768 + n] : Wf[k * 256 + ch];
        } else {
            int par = (k < 384) ? 0 : 1;
            int hh = (k - 128) & 255;
            if (g < 3) v = Uiou[(par * 256 + hh) * 768 + n];
            else {
                int kk = g - 3;
                v = Uf[(((kk * 2 + par) * 256) + hh) * 256 + ch];
            }
        }
        int chblk = (ch >> 5);
        int cl    = ch & 31;
        int kb    = k >> 6;
        int chunk = (k & 63) >> 3;
        int e     = k & 7;
        int brow  = g * 32 + cl;
        size_t dst = ((size_t)(chblk * 10 + kb) * 8 + chunk) * 1280 + brow * 8 + e;
        wtile[dst] = __float2bfloat16(v);
    }
    if (idx < 1280) {
        biasCat[idx] = (idx < 768) ? biou[idx] : bfv[idx & 255];
    }
}

// One tree level. Rows r = b*m + j (parents). A row = [x(128) | h_even | h_odd].
// Block tile: 128 rows x 32 channels x NG gate col-tiles (spaced 256 apart);
// each lane holds i,o,u,f0,f1 for its (row,ch) in registers -> fused epilogue.
// A LDS: [row][chunk^(row&7)][8] (XOR swizzle): DMA instrs cover 8 full cache
// lines AND fragment reads are 2-way-aliased (free). B LDS: linear copy of the
// pre-tiled weight image (8 full lines per instr), zero-conflict reads.
template <bool LEAF>
__global__ __launch_bounds__(256, 4)
void level_kernel(const float* __restrict__ arg_hot,
                  const bf16* __restrict__ wtile,
                  const float* __restrict__ biasCat,
                  const bf16* __restrict__ h_child,   // [(2M) rows][256]
                  const bf16* __restrict__ c_child,
                  bf16* __restrict__ h_out,           // [M rows][256]
                  bf16* __restrict__ c_out,
                  int m, int logm)
{
    constexpr int NG = LEAF ? 3 : 5;
    constexpr int KI = LEAF ? 2 : 10;    // k-blocks of 64

    const int M = BATCH * m;
    const int node_base = m - 1;

    __shared__ bf16 As[128 * 64];        // [row][cc][8] swizzled, 16 KB
    __shared__ bf16 Bs[8 * 160 * 8];     // [chunk][brow][8], 20 KB

    const int tid = threadIdx.x;

    // block swizzle: the 8 ch-blocks sharing an A m-tile land consecutive on one XCD
    int bid = blockIdx.x;
    int mtiles = gridDim.x >> 3;
    int mtile, chblk;
    if ((mtiles & 7) == 0) {
        int xcd = bid & 7;
        int seq = bid >> 3;
        chblk = seq & 7;
        mtile = ((seq >> 3) << 3) + xcd;
    } else {
        mtile = bid >> 3;
        chblk = bid & 7;
    }
    const int rbase  = mtile * 128;
    const int chbase = chblk * 32;

    const int lane = tid & 63;
    const int wave = tid >> 6;
    const int wr = wave & 1;   // row half (64 rows)
    const int wc = wave >> 1;  // channel half (16 ch)
    const int l15 = lane & 15;
    const int lq  = lane >> 4;
    const int xr7 = l15 & 7;   // fragment-read XOR key

    f32x4 acc[4][NG];
#pragma unroll
    for (int a = 0; a < 4; ++a)
#pragma unroll
        for (int g = 0; g < NG; ++g)
            acc[a][g] = (f32x4){0.f, 0.f, 0.f, 0.f};

    // A-DMA lane constants: slot s = t*64+lane -> row = t*8 + (lane>>3), cc = lane&7
    const int row_l = lane >> 3;
    const int cc_l  = lane & 7;
    const int aoff  = row_l * 512 + (cc_l ^ row_l) * 8;   // per-lane src offset

    // B source base for this block
    const bf16* wbase = wtile + (size_t)(chblk * 10) * 10240;

    // x staging source row (clamped for partial tiles)
    const int arow = tid & 127;
    const int rs = min(rbase + arow, M - 1);
    const float* xrow = arg_hot +
        ((size_t)(rs >> logm) * NNODES + node_base + (rs & (m - 1))) * 128;
    const int xswz_base = arow * 64;  // As row offset for x staging
    const int ar7 = arow & 7;

    for (int kb = 0; kb < KI; ++kb) {
        // ---- stage A ----
        if (LEAF || kb < 2) {
            // x region: fp32 -> bf16 packed converts, swizzled b128 LDS writes
            const float* xk = xrow + kb * 64;
#pragma unroll
            for (int j = 0; j < 4; ++j) {
                int chunk = (tid >> 7) + 2 * j;
                const float* src = xk + chunk * 8;
                float4 a = *(const float4*)src;
                float4 b = *(const float4*)(src + 4);
                union { int4 i4; __hip_bfloat162 h2[4]; } u;
                u.h2[0] = __float22bfloat162_rn(make_float2(a.x, a.y));
                u.h2[1] = __float22bfloat162_rn(make_float2(a.z, a.w));
                u.h2[2] = __float22bfloat162_rn(make_float2(b.x, b.y));
                u.h2[3] = __float22bfloat162_rn(make_float2(b.z, b.w));
                *(int4*)&As[xswz_base + ((chunk ^ ar7) * 8)] = u.i4;
            }
        } else {
            // h region: direct global->LDS DMA; each instr = 8 rows x one full
            // 128-B k-line (swizzle permutes 16-B chunks within the line)
            const bf16* hb = h_child + (size_t)rbase * 512 + (kb * 64 - 128) + aoff;
#pragma unroll
            for (int i = 0; i < 4; ++i) {
                int t = wave * 4 + i;
                async_copy16(hb + t * 8 * 512, &As[t * 512]);
            }
        }
        // ---- stage B: pure linear DMA of the pre-tiled image ----
        {
            const bf16* bsrc = wbase + (size_t)kb * 10240;
#pragma unroll
            for (int i = 0; i < 5; ++i) {
                int t = wave * 5 + i;
                async_copy16(bsrc + t * 512 + lane * 8, &Bs[t * 512]);
            }
        }
        __syncthreads();
        // ---- compute: 2 k-steps of 32, 4 x NG MFMAs each ----
#pragma unroll
        for (int ks = 0; ks < 2; ++ks) {
            int q = ks * 4 + lq;
            int qa = (q ^ xr7) * 8;
            bf16x8 af[4];
#pragma unroll
            for (int rt = 0; rt < 4; ++rt)
                af[rt] = *(const bf16x8*)&As[(wr * 64 + rt * 16 + l15) * 64 + qa];
#pragma unroll
            for (int g = 0; g < NG; ++g) {
                bf16x8 bfr = *(const bf16x8*)&Bs[q * 1280 + (g * 32 + wc * 16 + l15) * 8];
#pragma unroll
                for (int rt = 0; rt < 4; ++rt)
                    acc[rt][g] = __builtin_amdgcn_mfma_f32_16x16x32_bf16(
                        af[rt], bfr, acc[rt][g], 0, 0, 0);
            }
        }
        __syncthreads();
    }

    // ---- fused LSTM-cell epilogue (all gates in-register per lane) ----
    const int ch = chbase + wc * 16 + l15;
    const float b_i = biasCat[ch];
    const float b_o = biasCat[256 + ch];
    const float b_u = biasCat[512 + ch];
    const float b_f = LEAF ? 0.f : biasCat[768 + ch];

#pragma unroll
    for (int rt = 0; rt < 4; ++rt) {
#pragma unroll
        for (int ri = 0; ri < 4; ++ri) {
            int r = rbase + wr * 64 + rt * 16 + lq * 4 + ri;
            if (r < M) {
                float i = sigmoid_f(acc[rt][0][ri] + b_i);
                float o = sigmoid_f(acc[rt][1][ri] + b_o);
                float u = tanh_f(acc[rt][2][ri] + b_u);
                float cn;
                if (LEAF) {
                    cn = i * u;
                } else {
                    float f0 = sigmoid_f(acc[rt][3][ri] + b_f);
                    float f1 = sigmoid_f(acc[rt][4][ri] + b_f);
                    float c0 = __bfloat162float(c_child[(size_t)r * 512 + ch]);
                    float c1 = __bfloat162float(c_child[(size_t)r * 512 + 256 + ch]);
                    cn = i * u + f0 * c0 + f1 * c1;
                }
                float h = o * tanh_f(cn);
                h_out[(size_t)r * 256 + ch] = __float2bfloat16(h);
                c_out[(size_t)r * 256 + ch] = __float2bfloat16(cn);
            }
        }
    }
}

// actor head: logits = log(mask) + (h.w + b)*mask; softmax(logits/TEMP)
__global__ void head_kernel(const bf16* __restrict__ rootH,
                            const float* __restrict__ actor_w,
                            const float* __restrict__ actor_b,
                            const float* __restrict__ vmask,
                            float* __restrict__ out)
{
    int b = blockIdx.x;
    __shared__ float logits[NUM_OPS];
    int t = threadIdx.x;
    if (t < NUM_OPS) {
        const bf16* hr = rootH + b * 256;
        const float* w = actor_w + t * 256;
        float dot = 0.f;
        for (int hh = 0; hh < 256; ++hh)
            dot += __bfloat162float(hr[hh]) * w[hh];
        float mk = vmask[b * NUM_OPS + t];
        float lg = (mk > 0.f) ? (logf(mk) + (dot + actor_b[t]) * mk) : -INFINITY;
        logits[t] = lg / TEMP;
    }
    __syncthreads();
    if (t == 0) {
        float mx = -INFINITY;
        for (int o = 0; o < NUM_OPS; ++o) mx = fmaxf(mx, logits[o]);
        float s = 0.f;
        float e[NUM_OPS];
        for (int o = 0; o < NUM_OPS; ++o) { e[o] = __expf(logits[o] - mx); s += e[o]; }
        float inv = 1.f / s;
        for (int o = 0; o < NUM_OPS; ++o) out[b * NUM_OPS + o] = e[o] * inv;
    }
}

extern "C" void kernel_launch(void* const* d_in, const int* in_sizes, int n_in,
                              void* d_out, int out_size, void* d_ws, size_t ws_size,
                              hipStream_t stream)
{
    const float* arg_hot = (const float*)d_in[0];
    const float* Wiou    = (const float*)d_in[1];
    const float* biou    = (const float*)d_in[2];
    const float* Uiou    = (const float*)d_in[3];
    const float* Wf      = (const float*)d_in[4];
    const float* bfv     = (const float*)d_in[5];
    const float* Uf      = (const float*)d_in[6];
    const float* actor_w = (const float*)d_in[7];
    const float* actor_b = (const float*)d_in[8];
    const float* vmask   = (const float*)d_in[9];

    char* ws = (char*)d_ws;
    bf16*  wtile   = (bf16*)(ws + OFF_WTILE);
    float* biasCat = (float*)(ws + OFF_BIAS);
    bf16*  hA = (bf16*)(ws + OFF_HA);
    bf16*  cA = (bf16*)(ws + OFF_CA);
    bf16*  hB = (bf16*)(ws + OFF_HB);
    bf16*  cB = (bf16*)(ws + OFF_CB);

    init_weights<<<dim3((1280 * 640 + 255) / 256), 256, 0, stream>>>(
        Wiou, biou, Uiou, Wf, bfv, Uf, wtile, biasCat);

    // leaf level (l=11): m=2048, K=128, writes buffers A
    {
        int m = 2048;
        int mtiles = (BATCH * m + 127) / 128;   // 1024
        level_kernel<true><<<dim3(mtiles * 8), 256, 0, stream>>>(
            arg_hot, wtile, biasCat, nullptr, nullptr, hA, cA, m, 11);
    }
    // interior levels 10..0
    for (int l = 10; l >= 0; --l) {
        int m = 1 << l;
        int mtiles = (BATCH * m + 127) / 128;
        bf16 *hc, *cc, *ho, *co;
        if (l & 1) { hc = hB; cc = cB; ho = hA; co = cA; }
        else       { hc = hA; cc = cA; ho = hB; co = cB; }
        level_kernel<false><<<dim3(mtiles * 8), 256, 0, stream>>>(
            arg_hot, wtile, biasCat, hc, cc, ho, co, m, l);
    }
    // root h is in hB (level 0 writes B)
    head_kernel<<<dim3(BATCH), 64, 0, stream>>>(hB, actor_w, actor_b, vmask, (float*)d_out);
}